// Round 1
// 456.312 us; speedup vs baseline: 1.1852x; 1.1852x over previous
//
#include <hip/hip_runtime.h>
#include <math.h>

// ---------------- problem dims ----------------
#define B_   32
#define I_   2048
#define J_   16
#define C_   64
#define D_   32
#define CD_  2048           // C_*D_ "columns"
#define W_CSTR (I_*D_*J_)   // 1048576 floats
#define W_ISTR (D_*J_)      // 512 floats
#define X_BSTR (I_*J_)      // 32768 floats
#define EPS_ 1e-7f

typedef _Float16 half8 __attribute__((ext_vector_type(8)));
typedef float    f32x16 __attribute__((ext_vector_type(16)));

// MFMA geometry (v_mfma_f32_32x32x16_f16), SWAPPED orientation:
//   A = wf:  A[m][k]: m = lane&31 (= d), k = (lane>>5)*8 + e (= j)
//   B = xf:  B[k][n]: n = lane&31 (= b), k = (lane>>5)*8 + e (= j)
//   C/D:     col(n=b) = lane&31, row(m=d) = (r&3) + 8*(r>>2) + 4*(lane>>5)
// => u' has b in LANES, d in REGS: the routing dot over d is a per-lane
//    16-reg FMA chain + ONE __shfl_xor(,32), instead of a 31-shuffle fold.

__device__ __forceinline__ half8 wfrag_from_f32(const float* __restrict__ W,
                                                int c, int i, int l) {
  const float* wp = W + (size_t)c*W_CSTR + (size_t)i*W_ISTR
                      + (size_t)(l & 31)*J_ + ((l >> 5) << 3);
  float4 a = *(const float4*)wp;
  float4 b = *(const float4*)(wp + 4);
  half8 h;
  h[0]=(_Float16)a.x; h[1]=(_Float16)a.y; h[2]=(_Float16)a.z; h[3]=(_Float16)a.w;
  h[4]=(_Float16)b.x; h[5]=(_Float16)b.y; h[6]=(_Float16)b.z; h[7]=(_Float16)b.w;
  return h;
}

// ================= K0: pack x into B-fragment layout =================
__global__ __launch_bounds__(256) void k_xpack(const float* __restrict__ x,
                                               half8* __restrict__ xh) {
  const int tg = blockIdx.x*256 + threadIdx.x;    // 0..131071
  const int i = tg >> 6, l = tg & 63;
  const int b = l & 31, jb = (l >> 5) << 3;
  const float* xp = x + (size_t)b*X_BSTR + (size_t)i*J_ + jb;
  float4 a = *(const float4*)xp;
  float4 bb = *(const float4*)(xp + 4);
  half8 h;
  h[0]=(_Float16)a.x;  h[1]=(_Float16)a.y;  h[2]=(_Float16)a.z;  h[3]=(_Float16)a.w;
  h[4]=(_Float16)bb.x; h[5]=(_Float16)bb.y; h[6]=(_Float16)bb.z; h[7]=(_Float16)bb.w;
  xh[tg] = h;
}

// ================= K1: pass A (s0 partials + WB build) =================
// part layout: [chunk=64][c=64][d=32][b=32] f32
template<bool WRITE_WB>
__global__ __launch_bounds__(512, 4) void k_passA(const float* __restrict__ W,
                                                  const half8* __restrict__ xh,
                                                  float* __restrict__ part,
                                                  _Float16* __restrict__ WB) {
  const int t = threadIdx.x, l = t & 63, w = t >> 6;
  const int ic = blockIdx.x, c = blockIdx.y*8 + w;
  const int b = l & 31, h4 = (l >> 5)*4;
  f32x16 acc = {};
  #pragma unroll 4
  for (int ii = 0; ii < 32; ii++) {
    const int i = ic*32 + ii;
    half8 wf = wfrag_from_f32(W, c, i, l);
    half8 xf = xh[(size_t)i*64 + l];
    if (WRITE_WB)
      *(half8*)(WB + ((size_t)c*I_ + i)*512 + (size_t)l*8) = wf;
    acc = __builtin_amdgcn_mfma_f32_32x32x16_f16(wf, xf, acc, 0, 0, 0);
  }
  #pragma unroll
  for (int r = 0; r < 16; r++) {
    const int dr = (r & 3) + 8*(r >> 2) + h4;    // = d
    part[(size_t)ic*(B_*CD_) + ((size_t)c*32 + dr)*32 + b] = acc[r];
  }
}

// ================= K2: fused chunk-reduce + squash =================
// part layout [ch][c][d][b]; one block per c, 1024 threads (t = d*32+b).
// Coalesced chunk-sum, LDS tree-reduce over d for ||s||^2.
// TOUT=false: write v1[c][d][b] (coalesced). TOUT=true: write out[b][c][d].
template<bool TOUT>
__global__ __launch_bounds__(1024) void k_redsquash(const float* __restrict__ part,
                                                    float* __restrict__ outp,
                                                    float scale) {
  __shared__ float SN[1024];
  const int c = blockIdx.x, t = threadIdx.x;
  const int d = t >> 5, b = t & 31;
  float s = 0.f;
  #pragma unroll 8
  for (int ch = 0; ch < 64; ch++) s += part[(size_t)ch*(B_*CD_) + c*1024 + t];
  s *= scale;
  SN[t] = s*s;
  __syncthreads();
  #pragma unroll
  for (int st = 16; st >= 1; st >>= 1) {
    if (d < st) SN[t] += SN[t + st*32];
    __syncthreads();
  }
  const float sn = SN[b];
  const float sc = sn / ((1.f + sn) * sqrtf(sn + EPS_));
  const float val = s*sc;
  if (TOUT) outp[(size_t)b*CD_ + c*32 + d] = val;    // final [b][c][d]
  else      outp[(size_t)c*1024 + t] = val;          // v1 [c][d][b]
}

// ================= K3: b-logits -> b1[i][c][b] =================
// Swapped-orientation u' (b in lanes, d in regs): per-lane dot with hoisted
// v1 fragment + one xor32 shuffle. No fold network.
template<bool USE_WB>
__global__ __launch_bounds__(512, 4) void k_blogit(const float* __restrict__ W,
                                                   const _Float16* __restrict__ WB,
                                                   const half8* __restrict__ xh,
                                                   const float* __restrict__ v1,
                                                   float* __restrict__ b1) {
  const int t = threadIdx.x, l = t & 63, w = t >> 6;
  const int ic = blockIdx.x, c = blockIdx.y*8 + w;
  const int b = l & 31, h4 = (l >> 5)*4;

  float v1r[16];                                  // v1[c][d(r)][b], i-independent
  #pragma unroll
  for (int r = 0; r < 16; r++) {
    const int dr = (r & 3) + 8*(r >> 2) + h4;
    v1r[r] = v1[(size_t)c*1024 + dr*32 + b];
  }

  #pragma unroll 4
  for (int ii = 0; ii < 32; ii++) {
    const int i = ic*32 + ii;
    half8 wf = USE_WB ? *(const half8*)(WB + ((size_t)c*I_ + i)*512 + (size_t)l*8)
                      : wfrag_from_f32(W, c, i, l);
    half8 xf = xh[(size_t)i*64 + l];
    f32x16 z = {};
    f32x16 u = __builtin_amdgcn_mfma_f32_32x32x16_f16(wf, xf, z, 0, 0, 0);
    float y = 0.f;
    #pragma unroll
    for (int r = 0; r < 16; r++) y += u[r]*v1r[r]; // sum over this lane's 16 d's
    y += __shfl_xor(y, 32);                        // + other half's 16 d's
    if (l < 32)
      b1[((size_t)i*64 + c)*32 + b] = y;
  }
}

// ================= K4: softmax over c, [i][c][b] tiles =================
__global__ __launch_bounds__(256) void k_softmaxT(const float* __restrict__ b1,
                                                  float* __restrict__ c2) {
  __shared__ float ST[2048];
  __shared__ float PM[256], PS[256];
  const int i = blockIdx.x, t = threadIdx.x;
  const float* src = b1 + (size_t)i*2048;
  *(float4*)(ST + t*8)     = *(const float4*)(src + t*8);
  *(float4*)(ST + t*8 + 4) = *(const float4*)(src + t*8 + 4);
  __syncthreads();
  const int b = t & 31, ck = t >> 5;
  float m = -1e30f;
  #pragma unroll
  for (int cc = 0; cc < 8; cc++) m = fmaxf(m, ST[(ck*8 + cc)*32 + b]);
  PM[t] = m;
  __syncthreads();
  #pragma unroll
  for (int k = 0; k < 8; k++) m = fmaxf(m, PM[k*32 + b]);
  float s = 0.f;
  #pragma unroll
  for (int cc = 0; cc < 8; cc++) {
    const int idx = (ck*8 + cc)*32 + b;
    const float e = __expf(ST[idx] - m);
    s += e;
    ST[idx] = e;
  }
  PS[t] = s;
  __syncthreads();
  s = 0.f;
  #pragma unroll
  for (int k = 0; k < 8; k++) s += PS[k*32 + b];
  const float inv = 1.f / s;
  float* dst = c2 + (size_t)i*2048;
  #pragma unroll
  for (int cc = 0; cc < 8; cc++) {
    const int idx = (ck*8 + cc)*32 + b;
    dst[idx] = ST[idx] * inv;
  }
}

// ================= K5: pass B2 (s2 partials) =================
// Swapped orientation: c2 weight is one coalesced per-lane load.
template<bool USE_WB>
__global__ __launch_bounds__(512, 4) void k_passB2(const float* __restrict__ W,
                                                   const _Float16* __restrict__ WB,
                                                   const half8* __restrict__ xh,
                                                   const float* __restrict__ c2,
                                                   float* __restrict__ part) {
  const int t = threadIdx.x, l = t & 63, w = t >> 6;
  const int ic = blockIdx.x, c = blockIdx.y*8 + w;
  const int b = l & 31, h4 = (l >> 5)*4;
  f32x16 s2 = {};
  #pragma unroll 4
  for (int ii = 0; ii < 32; ii++) {
    const int i = ic*32 + ii;
    half8 wf = USE_WB ? *(const half8*)(WB + ((size_t)c*I_ + i)*512 + (size_t)l*8)
                      : wfrag_from_f32(W, c, i, l);
    half8 xf = xh[(size_t)i*64 + l];
    f32x16 z = {};
    f32x16 u = __builtin_amdgcn_mfma_f32_32x32x16_f16(wf, xf, z, 0, 0, 0);
    const float cv = c2[((size_t)i*64 + c)*32 + b];
    #pragma unroll
    for (int r = 0; r < 16; r++) s2[r] += cv*u[r];
  }
  #pragma unroll
  for (int r = 0; r < 16; r++) {
    const int dr = (r & 3) + 8*(r >> 2) + h4;
    part[(size_t)ic*(B_*CD_) + ((size_t)c*32 + dr)*32 + b] = s2[r];
  }
}

// ================= host =================
extern "C" void kernel_launch(void* const* d_in, const int* in_sizes, int n_in,
                              void* d_out, int out_size, void* d_ws, size_t ws_size,
                              hipStream_t stream) {
  (void)in_sizes; (void)n_in; (void)out_size;
  const float* x = (const float*)d_in[0];   // [32, 2048, 16] f32
  const float* W = (const float*)d_in[1];   // [64, 2048, 32, 16] f32
  float* out = (float*)d_out;               // [32, 64, 32] f32

  const size_t MiB = 1024*1024;
  char* ws = (char*)d_ws;
  const bool big = ws_size >= 163*MiB;

  _Float16* WB; float *part, *b1, *c2, *xhp, *v1;
  if (big) {
    WB    = (_Float16*)(ws);                //   128 MiB f16 W fragments
    part  = (float*)(ws + 128*MiB);         //    16 MiB
    b1    = part;                           //    alias (sequential lifetime)
    c2    = (float*)(ws + 144*MiB);         //    16 MiB
    xhp   = (float*)(ws + 160*MiB);         //     2 MiB
    v1    = (float*)(ws + 162*MiB);         //   256 KiB
  } else {
    WB    = nullptr;
    part  = (float*)(ws);
    b1    = part;
    c2    = (float*)(ws + 16*MiB);
    xhp   = (float*)(ws + 32*MiB);
    v1    = (float*)(ws + 34*MiB);
  }
  half8* xh = (half8*)xhp;

  k_xpack<<<512, 256, 0, stream>>>(x, xh);
  if (big) k_passA<true ><<<dim3(64, 8), 512, 0, stream>>>(W, xh, part, WB);
  else     k_passA<false><<<dim3(64, 8), 512, 0, stream>>>(W, xh, part, WB);
  k_redsquash<false><<<64, 1024, 0, stream>>>(part, v1, 1.f/64.f);   // v1[c][d][b]
  if (big) k_blogit<true ><<<dim3(64, 8), 512, 0, stream>>>(W, WB, xh, v1, b1);
  else     k_blogit<false><<<dim3(64, 8), 512, 0, stream>>>(W, WB, xh, v1, b1);
  k_softmaxT<<<2048, 256, 0, stream>>>(b1, c2);
  if (big) k_passB2<true ><<<dim3(64, 8), 512, 0, stream>>>(W, WB, xh, c2, part);
  else     k_passB2<false><<<dim3(64, 8), 512, 0, stream>>>(W, WB, xh, c2, part);
  k_redsquash<true><<<64, 1024, 0, stream>>>(part, out, 1.f);
}